// Round 4
// baseline (88.901 us; speedup 1.0000x reference)
//
#include <hip/hip_runtime.h>

// NetVLAD MI355X v4: SPLIT=8 (256 blocks x 512 thr), fused reduce+norm with
// device-scope spin barrier (counter init'd by kernel 1 -> poison-safe).
// Phase 1: scores = 2*F.C^T - |c|^2, split-bf16 MFMA 16x16x32 (3 terms) [verified r2/r3]
// Phase 2: vlad_pos = simT x F_T via bf16 MFMA, chunk-XOR swizzled LDS [verified r3]

#define NB    32
#define SPLIT 8

typedef short short8 __attribute__((ext_vector_type(8)));
typedef float f32x4  __attribute__((ext_vector_type(4)));

__device__ __forceinline__ float bf2f(unsigned short u) {
    return __uint_as_float(((unsigned)u) << 16);
}
__device__ __forceinline__ unsigned short f2bf(float f) {
    unsigned u = __float_as_uint(f);
    return (unsigned short)((u + 0x7fffu + ((u >> 16) & 1u)) >> 16);
}

// LDS map (84,224 B -> 1 block/CU, 8 waves):
// [    0,16384) centHi bf16[64][128], ushort4 idx: k*32 + (d4 ^ ((k&7)<<1))
// [16384,32768) centLo same layout
// [32768,65536) FT bf16[128][128]: elem d*128 + (((p>>3)^(d&15))<<3) + (p&7)
// [65536,81920) ST bf16[64][128]:  elem k*128 + (((p>>3)^(k&15))<<3) + (p&7)
// [81920,82176) c2 f32[64]
// [82176,84224) ssumW f32[8][64]
__global__ __launch_bounds__(512, 1)
void netvlad_main(const float* __restrict__ feat,
                  const float* __restrict__ cent,
                  float* __restrict__ partial,
                  float* __restrict__ ssumG,
                  float* __restrict__ sqG,
                  unsigned int* __restrict__ ctr)
{
    __shared__ __align__(16) char smem[84224];
    ushort4*        centHi = (ushort4*)smem;
    ushort4*        centLo = (ushort4*)(smem + 16384);
    unsigned short* FT     = (unsigned short*)(smem + 32768);
    unsigned short* ST     = (unsigned short*)(smem + 65536);
    float*          c2L    = (float*)(smem + 81920);
    float*          ssumW  = (float*)(smem + 82176);

    const int tid = threadIdx.x;
    const int bs  = blockIdx.x;
    const int b   = bs >> 3;
    const int n0  = (bs & 7) * 128;

    // init barrier state for kernel 2 (visible at kernel boundary)
    if (bs == 0 && tid == 0) { sqG[0] = 0.f; ctr[0] = 0u; }

    const float4* cent4 = (const float4*)cent + (size_t)b * 2048;
    const float4* feat4 = (const float4*)feat + ((size_t)b * 1024 + n0) * 32;

    const int w    = tid >> 6;          // wave 0..7
    const int lane = tid & 63;
    const int lr   = lane & 15;
    const int lg   = lane >> 4;
    const int prow = 16 * w + lr;       // this lane's pixel row (0..127)

    // ---- A-frags: global -> regs, split bf16 hi/lo; scatter FT (hi) ----
    short8 ah[4], al[4];
    #pragma unroll
    for (int kt = 0; kt < 4; ++kt) {
        float4 fa = feat4[prow * 32 + kt * 8 + 2 * lg + 0];
        float4 fb = feat4[prow * 32 + kt * 8 + 2 * lg + 1];
        float fv[8] = { fa.x, fa.y, fa.z, fa.w, fb.x, fb.y, fb.z, fb.w };
        #pragma unroll
        for (int j = 0; j < 8; ++j) {
            unsigned short h = f2bf(fv[j]);
            ah[kt][j] = (short)h;
            al[kt][j] = (short)f2bf(fv[j] - bf2f(h));
            int d = kt * 32 + 8 * lg + j;
            FT[d * 128 + ((((prow >> 3) ^ (d & 15))) << 3) + (prow & 7)] = h;
        }
    }

    // ---- stage centers as bf16 hi/lo (swizzled) ----
    #pragma unroll
    for (int it = 0; it < 4; ++it) {
        int g  = it * 512 + tid;
        int k  = g >> 5;
        int d4 = g & 31;
        float4 v = cent4[g];
        ushort4 h, l;
        h.x = f2bf(v.x); l.x = f2bf(v.x - bf2f(h.x));
        h.y = f2bf(v.y); l.y = f2bf(v.y - bf2f(h.y));
        h.z = f2bf(v.z); l.z = f2bf(v.z - bf2f(h.z));
        h.w = f2bf(v.w); l.w = f2bf(v.w - bf2f(h.w));
        int idx = k * 32 + (d4 ^ ((k & 7) << 1));
        centHi[idx] = h; centLo[idx] = l;
    }

    // ---- c2[k] from global f32, all 512 threads (k=tid>>3, q=tid&7) ----
    {
        int k = tid >> 3, q = tid & 7;
        float a = 0.f;
        #pragma unroll
        for (int j = 0; j < 4; ++j) {
            float4 v = cent4[k * 32 + q * 4 + j];
            a += v.x * v.x + v.y * v.y + v.z * v.z + v.w * v.w;
        }
        a += __shfl_xor(a, 1);
        a += __shfl_xor(a, 2);
        a += __shfl_xor(a, 4);
        if (q == 0) c2L[k] = a;
    }
    __syncthreads();

    float c2r[4];
    #pragma unroll
    for (int nt = 0; nt < 4; ++nt) c2r[nt] = c2L[nt * 16 + lr];

    // ---- phase 1: scores via split-bf16 MFMA ----
    f32x4 acc[4];
    #pragma unroll
    for (int nt = 0; nt < 4; ++nt) acc[nt] = (f32x4){0.f, 0.f, 0.f, 0.f};
    #pragma unroll
    for (int kt = 0; kt < 4; ++kt) {
        #pragma unroll
        for (int nt = 0; nt < 4; ++nt) {
            int c  = nt * 16 + lr;
            int ch = c * 16 + ((kt * 4 + lg) ^ (c & 7));
            short8 bh = *(const short8*)(smem + ch * 16);
            short8 bl = *(const short8*)(smem + 16384 + ch * 16);
            acc[nt] = __builtin_amdgcn_mfma_f32_16x16x32_bf16(ah[kt], bh, acc[nt], 0, 0, 0);
            acc[nt] = __builtin_amdgcn_mfma_f32_16x16x32_bf16(ah[kt], bl, acc[nt], 0, 0, 0);
            acc[nt] = __builtin_amdgcn_mfma_f32_16x16x32_bf16(al[kt], bh, acc[nt], 0, 0, 0);
        }
    }

    // ---- softmax; write ST bf16; ssum partials ----
    float ssp[4] = {0.f, 0.f, 0.f, 0.f};
    #pragma unroll
    for (int r = 0; r < 4; ++r) {
        float s[4];
        #pragma unroll
        for (int nt = 0; nt < 4; ++nt) s[nt] = 2.f * acc[nt][r] - c2r[nt];
        float m = fmaxf(fmaxf(s[0], s[1]), fmaxf(s[2], s[3]));
        #pragma unroll
        for (int o = 8; o >= 1; o >>= 1) m = fmaxf(m, __shfl_xor(m, o));
        float e[4], t = 0.f;
        #pragma unroll
        for (int nt = 0; nt < 4; ++nt) { e[nt] = __expf(s[nt] - m); t += e[nt]; }
        #pragma unroll
        for (int o = 8; o >= 1; o >>= 1) t += __shfl_xor(t, o);
        float inv = __builtin_amdgcn_rcpf(t);
        int p = 16 * w + 4 * lg + r;
        #pragma unroll
        for (int nt = 0; nt < 4; ++nt) {
            int k = nt * 16 + lr;
            float val = e[nt] * inv;
            ssp[nt] += val;
            ST[k * 128 + ((((p >> 3) ^ (k & 15))) << 3) + (p & 7)] = f2bf(val);
        }
    }
    #pragma unroll
    for (int nt = 0; nt < 4; ++nt) {
        float v = ssp[nt];
        v += __shfl_xor(v, 16);
        v += __shfl_xor(v, 32);
        if (lg == 0) ssumW[w * 64 + nt * 16 + lr] = v;
    }
    __syncthreads();

    if (tid < 64) {
        float s = 0.f;
        #pragma unroll
        for (int ww = 0; ww < 8; ++ww) s += ssumW[ww * 64 + tid];
        ssumG[bs * 64 + tid] = s;
    }

    // ---- phase 2: vlad_pos = simT x F_T; wave w: k-tile w&3, d-half w>>2 ----
    f32x4 vac[4];
    #pragma unroll
    for (int dt = 0; dt < 4; ++dt) vac[dt] = (f32x4){0.f, 0.f, 0.f, 0.f};
    const int kt2  = w & 3;
    const int dh   = w >> 2;
    const int krow = 16 * kt2 + lr;
    #pragma unroll
    for (int ks = 0; ks < 4; ++ks) {
        int cA = (ks * 4 + lg) ^ (krow & 15);
        short8 af = *(const short8*)(ST + krow * 128 + (cA << 3));
        #pragma unroll
        for (int dt = 0; dt < 4; ++dt) {
            int d  = dh * 64 + dt * 16 + lr;
            int cB = (ks * 4 + lg) ^ (d & 15);
            short8 bf = *(const short8*)(FT + d * 128 + (cB << 3));
            vac[dt] = __builtin_amdgcn_mfma_f32_16x16x32_bf16(af, bf, vac[dt], 0, 0, 0);
        }
    }

    // ---- write vlad_pos partial ----
    float* outp = partial + (size_t)bs * 8192;
    #pragma unroll
    for (int r = 0; r < 4; ++r) {
        int k = 16 * kt2 + 4 * lg + r;
        #pragma unroll
        for (int dt = 0; dt < 4; ++dt)
            outp[k * 128 + dh * 64 + dt * 16 + lr] = vac[dt][r];
    }
}

// Fused reduce + global-norm + scale, single kernel with device-scope barrier.
// 256 blocks x 256 threads (<= 256 CUs -> co-resident; ctr/sqG init'd by kernel 1).
__global__ __launch_bounds__(256)
void netvlad_finish(const float* __restrict__ partial,
                    const float* __restrict__ cent,
                    const float* __restrict__ ssumG,
                    float* __restrict__ sqG,
                    unsigned int* __restrict__ ctr,
                    float* __restrict__ out) {
    __shared__ float wsum[4];
    const int tid = threadIdx.x;
    int idx = blockIdx.x * 256 + tid;   // float4 id over (b, k, d4)
    int b   = idx >> 11;
    int rem = idx & 2047;
    int k   = rem >> 5;
    const float4* p4 = (const float4*)partial;
    float4 a = make_float4(0.f, 0.f, 0.f, 0.f);
    float  ss = 0.f;
    #pragma unroll
    for (int s = 0; s < SPLIT; ++s) {
        float4 v = p4[((size_t)(b * SPLIT + s)) * 2048 + rem];
        a.x += v.x; a.y += v.y; a.z += v.z; a.w += v.w;
        ss += ssumG[(b * SPLIT + s) * 64 + k];
    }
    float4 c4 = ((const float4*)cent)[b * 2048 + rem];
    a.x -= ss * c4.x; a.y -= ss * c4.y; a.z -= ss * c4.z; a.w -= ss * c4.w;

    float sq = a.x * a.x + a.y * a.y + a.z * a.z + a.w * a.w;
    #pragma unroll
    for (int o = 32; o >= 1; o >>= 1) sq += __shfl_xor(sq, o);
    if ((tid & 63) == 0) wsum[tid >> 6] = sq;
    __syncthreads();
    if (tid == 0) {
        atomicAdd(sqG, wsum[0] + wsum[1] + wsum[2] + wsum[3]);
        __threadfence();
        atomicAdd(ctr, 1u);
        while (__hip_atomic_load(ctr, __ATOMIC_ACQUIRE, __HIP_MEMORY_SCOPE_AGENT) < 256u)
            __builtin_amdgcn_s_sleep(8);
    }
    __syncthreads();

    float t = __hip_atomic_load(sqG, __ATOMIC_RELAXED, __HIP_MEMORY_SCOPE_AGENT);
    float inv = __builtin_amdgcn_rcpf(sqrtf(fmaxf(t, 1e-12f)));
    ((float4*)out)[idx] = make_float4(a.x * inv, a.y * inv, a.z * inv, a.w * inv);
}

extern "C" void kernel_launch(void* const* d_in, const int* in_sizes, int n_in,
                              void* d_out, int out_size, void* d_ws, size_t ws_size,
                              hipStream_t stream) {
    const float* feat = (const float*)d_in[0];   // (32,32,32,128)
    const float* cent = (const float*)d_in[1];   // (32,64,128)
    float* out = (float*)d_out;                  // (32,8192)

    char* ws = (char*)d_ws;
    const size_t partial_bytes = (size_t)NB * SPLIT * 64 * 128 * sizeof(float); // 8 MB
    const size_t ssum_bytes    = (size_t)NB * SPLIT * 64 * sizeof(float);       // 64 KB
    float*        partial = (float*)ws;
    float*        ssumG   = (float*)(ws + partial_bytes);
    float*        sqG     = (float*)(ws + partial_bytes + ssum_bytes);
    unsigned int* ctr     = (unsigned int*)(ws + partial_bytes + ssum_bytes + 256);

    netvlad_main  <<<NB * SPLIT, 512, 0, stream>>>(feat, cent, partial, ssumG, sqG, ctr);
    netvlad_finish<<<NB * SPLIT, 256, 0, stream>>>(partial, cent, ssumG, sqG, ctr, out);
}

// Round 6
// 79.872 us; speedup vs baseline: 1.1130x; 1.1130x over previous
//
#include <hip/hip_runtime.h>
#include <hip/hip_bf16.h>

// NetVLAD MI355X v5 (resubmit — r5 bench was a broker timeout, never measured):
// r3 geometry (SPLIT=16, 256-thr blocks, 2 blocks/CU) + prep kernel that
// pre-converts centers to the swizzled bf16 hi/lo LDS image (1 MB in ws) and
// precomputes c2[b][k]. Main kernel: pure-copy center staging, c2 from global,
// one fewer barrier, native RNE f32->bf16 conversions.
// Phase 1: scores = 2*F.C^T - |c|^2, split-bf16 MFMA (3 terms) [verified r2-r4]
// Phase 2: vlad_pos = simT x F_T bf16 MFMA, chunk-XOR swizzles [verified r3]

#define NB    32
#define SPLIT 16

typedef short short8 __attribute__((ext_vector_type(8)));
typedef float f32x4  __attribute__((ext_vector_type(4)));

__device__ __forceinline__ float bf2f(unsigned short u) {
    return __uint_as_float(((unsigned)u) << 16);
}
__device__ __forceinline__ unsigned short f2bf(float f) {
    __hip_bfloat16 h = __float2bfloat16(f);   // RNE; compiler can pair into v_cvt_pk_bf16_f32
    unsigned short u;
    __builtin_memcpy(&u, &h, 2);
    return u;
}
__device__ __forceinline__ int swz3(int x) { return (x ^ (x >> 3)) & 7; }

// ---- prep: centers -> per-batch swizzled bf16 hi/lo LDS image + c2[b][k] ----
// cws per batch: 4096 ushort4 (hi slots [0,2048), lo slots [2048,4096))
// slot(k,d4) = k*32 + (d4 ^ ((k&7)<<1))
__global__ __launch_bounds__(256)
void netvlad_prep(const float* __restrict__ cent,
                  ushort4* __restrict__ cws,
                  float* __restrict__ c2G) {
    const int tid = threadIdx.x;
    const int bi  = blockIdx.x;      // 256 blocks = 32 b x 8 k-groups
    const int b   = bi >> 3;
    const int kg  = bi & 7;
    const int kk  = tid >> 5;        // 0..7
    const int d4  = tid & 31;
    const int k   = kg * 8 + kk;
    float4 v = ((const float4*)cent)[(size_t)b * 2048 + k * 32 + d4];
    ushort4 h, l;
    h.x = f2bf(v.x); l.x = f2bf(v.x - bf2f(h.x));
    h.y = f2bf(v.y); l.y = f2bf(v.y - bf2f(h.y));
    h.z = f2bf(v.z); l.z = f2bf(v.z - bf2f(h.z));
    h.w = f2bf(v.w); l.w = f2bf(v.w - bf2f(h.w));
    int slot = k * 32 + (d4 ^ ((k & 7) << 1));
    cws[(size_t)b * 4096 + slot]        = h;
    cws[(size_t)b * 4096 + 2048 + slot] = l;
    float a = v.x * v.x + v.y * v.y + v.z * v.z + v.w * v.w;
    a += __shfl_xor(a, 1);
    a += __shfl_xor(a, 2);
    a += __shfl_xor(a, 4);
    a += __shfl_xor(a, 8);
    a += __shfl_xor(a, 16);
    if (d4 == 0) c2G[b * 64 + k] = a;
}

// LDS map (58,368 B -> 2 blocks/CU):
// [    0,16384) centHi bf16[64][128], ushort4 slot: k*32 + (d4 ^ ((k&7)<<1))
// [16384,32768) centLo same layout
// [32768,49152) F_T  bf16[128][64], elem: d*64 + (((p>>3) ^ swz3(d))<<3) + (p&7)
// [49152,57344) simT bf16[64][64],  elem: k*64 + (((p>>3) ^ swz3(k))<<3) + (p&7)
// [57344,58368) ssumW f32[4][64]
__global__ __launch_bounds__(256, 2)
void netvlad_main(const float* __restrict__ feat,
                  const ushort4* __restrict__ cws,
                  const float* __restrict__ c2G,
                  float* __restrict__ partial,
                  float* __restrict__ ssumG)
{
    __shared__ __align__(16) char smem[58368];
    unsigned short* FT    = (unsigned short*)(smem + 32768);
    unsigned short* ST    = (unsigned short*)(smem + 49152);
    float*          ssumW = (float*)(smem + 57344);

    const int tid = threadIdx.x;
    const int bs  = blockIdx.x;
    const int b   = bs >> 4;
    const int n0  = (bs & 15) * 64;

    // ---- stage pre-swizzled center image: pure 16B copies ----
    const uint4* csrc = (const uint4*)(cws + (size_t)b * 4096);
    #pragma unroll
    for (int it = 0; it < 8; ++it)
        ((uint4*)smem)[it * 256 + tid] = csrc[it * 256 + tid];

    const float4* feat4 = (const float4*)feat + ((size_t)b * 1024 + n0) * 32;

    const int w    = tid >> 6;
    const int lane = tid & 63;
    const int lr   = lane & 15;
    const int lg   = lane >> 4;
    const int prow = 16 * w + lr;     // pixel row 0..63

    // ---- c2 from global (L2-hit scalar loads, no LDS phase) ----
    float c2r[4];
    #pragma unroll
    for (int nt = 0; nt < 4; ++nt) c2r[nt] = c2G[b * 64 + nt * 16 + lr];

    // ---- A-frags: global -> regs, split bf16 hi/lo; scatter FT (hi) ----
    short8 ah[4], al[4];
    #pragma unroll
    for (int kt = 0; kt < 4; ++kt) {
        float4 fa = feat4[prow * 32 + kt * 8 + 2 * lg + 0];
        float4 fb = feat4[prow * 32 + kt * 8 + 2 * lg + 1];
        float fv[8] = { fa.x, fa.y, fa.z, fa.w, fb.x, fb.y, fb.z, fb.w };
        #pragma unroll
        for (int j = 0; j < 8; ++j) {
            unsigned short h = f2bf(fv[j]);
            ah[kt][j] = (short)h;
            al[kt][j] = (short)f2bf(fv[j] - bf2f(h));
            int d = kt * 32 + 8 * lg + j;
            FT[d * 64 + ((((prow >> 3) ^ swz3(d))) << 3) + (prow & 7)] = h;
        }
    }
    __syncthreads();

    // ---- phase 1: scores via split-bf16 MFMA ----
    f32x4 acc[4];
    #pragma unroll
    for (int nt = 0; nt < 4; ++nt) acc[nt] = (f32x4){0.f, 0.f, 0.f, 0.f};
    #pragma unroll
    for (int kt = 0; kt < 4; ++kt) {
        #pragma unroll
        for (int nt = 0; nt < 4; ++nt) {
            int c  = nt * 16 + lr;
            int ch = c * 16 + ((kt * 4 + lg) ^ (c & 7));
            short8 bh = *(const short8*)(smem + ch * 16);
            short8 bl = *(const short8*)(smem + 16384 + ch * 16);
            acc[nt] = __builtin_amdgcn_mfma_f32_16x16x32_bf16(ah[kt], bh, acc[nt], 0, 0, 0);
            acc[nt] = __builtin_amdgcn_mfma_f32_16x16x32_bf16(ah[kt], bl, acc[nt], 0, 0, 0);
            acc[nt] = __builtin_amdgcn_mfma_f32_16x16x32_bf16(al[kt], bh, acc[nt], 0, 0, 0);
        }
    }

    // ---- softmax; write simT bf16; ssum partials ----
    float ssp[4] = {0.f, 0.f, 0.f, 0.f};
    #pragma unroll
    for (int r = 0; r < 4; ++r) {
        float s[4];
        #pragma unroll
        for (int nt = 0; nt < 4; ++nt) s[nt] = 2.f * acc[nt][r] - c2r[nt];
        float m = fmaxf(fmaxf(s[0], s[1]), fmaxf(s[2], s[3]));
        #pragma unroll
        for (int o = 8; o >= 1; o >>= 1) m = fmaxf(m, __shfl_xor(m, o));
        float e[4], t = 0.f;
        #pragma unroll
        for (int nt = 0; nt < 4; ++nt) { e[nt] = __expf(s[nt] - m); t += e[nt]; }
        #pragma unroll
        for (int o = 8; o >= 1; o >>= 1) t += __shfl_xor(t, o);
        float inv = __builtin_amdgcn_rcpf(t);
        int p = 16 * w + 4 * lg + r;
        #pragma unroll
        for (int nt = 0; nt < 4; ++nt) {
            int k = nt * 16 + lr;
            float val = e[nt] * inv;
            ssp[nt] += val;
            ST[k * 64 + ((((p >> 3) ^ swz3(k))) << 3) + (p & 7)] = f2bf(val);
        }
    }
    #pragma unroll
    for (int nt = 0; nt < 4; ++nt) {
        float v = ssp[nt];
        v += __shfl_xor(v, 16);
        v += __shfl_xor(v, 32);
        if (lg == 0) ssumW[w * 64 + nt * 16 + lr] = v;
    }
    __syncthreads();

    if (tid < 64)
        ssumG[bs * 64 + tid] = ssumW[tid] + ssumW[64 + tid] + ssumW[128 + tid] + ssumW[192 + tid];

    // ---- phase 2: vlad_pos = simT x F_T via MFMA; wave w owns k-tile w ----
    f32x4 vac[8];
    #pragma unroll
    for (int dt = 0; dt < 8; ++dt) vac[dt] = (f32x4){0.f, 0.f, 0.f, 0.f};
    const int krow = 16 * w + lr;
    #pragma unroll
    for (int ks = 0; ks < 2; ++ks) {
        int cA = (ks * 4 + lg) ^ swz3(krow);
        short8 af = *(const short8*)(ST + krow * 64 + (cA << 3));
        #pragma unroll
        for (int dt = 0; dt < 8; ++dt) {
            int d  = dt * 16 + lr;
            int cB = (ks * 4 + lg) ^ swz3(d);
            short8 bf = *(const short8*)(FT + d * 64 + (cB << 3));
            vac[dt] = __builtin_amdgcn_mfma_f32_16x16x32_bf16(af, bf, vac[dt], 0, 0, 0);
        }
    }

    // ---- write vlad_pos partial ----
    float* outp = partial + (size_t)bs * 8192;
    #pragma unroll
    for (int r = 0; r < 4; ++r) {
        int k = 16 * w + 4 * lg + r;
        #pragma unroll
        for (int dt = 0; dt < 8; ++dt)
            outp[k * 128 + dt * 16 + lr] = vac[dt][r];
    }
}

__global__ __launch_bounds__(256)
void netvlad_reduce(const float* __restrict__ partial,
                    const float* __restrict__ cent,
                    const float* __restrict__ ssumG,
                    float* __restrict__ vlad,
                    float* __restrict__ sqpart) {
    __shared__ float wsum[4];
    int idx = blockIdx.x * 256 + threadIdx.x;   // float4 id over (b, k, d4)
    int b   = idx >> 11;
    int rem = idx & 2047;
    int k   = rem >> 5;
    const float4* p4 = (const float4*)partial;
    float4 a = make_float4(0.f, 0.f, 0.f, 0.f);
    float  ss = 0.f;
    #pragma unroll
    for (int s = 0; s < SPLIT; ++s) {
        float4 v = p4[((size_t)(b * SPLIT + s)) * 2048 + rem];
        a.x += v.x; a.y += v.y; a.z += v.z; a.w += v.w;
        ss += ssumG[(b * SPLIT + s) * 64 + k];
    }
    float4 c4 = ((const float4*)cent)[b * 2048 + rem];
    a.x -= ss * c4.x; a.y -= ss * c4.y; a.z -= ss * c4.z; a.w -= ss * c4.w;
    ((float4*)vlad)[idx] = a;
    float sq = a.x * a.x + a.y * a.y + a.z * a.z + a.w * a.w;
    #pragma unroll
    for (int o = 32; o >= 1; o >>= 1) sq += __shfl_xor(sq, o);
    if ((threadIdx.x & 63) == 0) wsum[threadIdx.x >> 6] = sq;
    __syncthreads();
    if (threadIdx.x == 0) sqpart[blockIdx.x] = wsum[0] + wsum[1] + wsum[2] + wsum[3];
}

__global__ __launch_bounds__(256)
void netvlad_norm(const float* __restrict__ vlad,
                  const float* __restrict__ sqpart,
                  float* __restrict__ out) {
    const float4* sq4 = (const float4*)sqpart;
    float4 v = sq4[threadIdx.x & 63];
    float t = v.x + v.y + v.z + v.w;
    #pragma unroll
    for (int o = 32; o >= 1; o >>= 1) t += __shfl_xor(t, o);
    float inv = __builtin_amdgcn_rcpf(sqrtf(fmaxf(t, 1e-12f)));
    int idx = blockIdx.x * 256 + threadIdx.x;
    float4 x = ((const float4*)vlad)[idx];
    ((float4*)out)[idx] = make_float4(x.x * inv, x.y * inv, x.z * inv, x.w * inv);
}

extern "C" void kernel_launch(void* const* d_in, const int* in_sizes, int n_in,
                              void* d_out, int out_size, void* d_ws, size_t ws_size,
                              hipStream_t stream) {
    const float* feat = (const float*)d_in[0];   // (32,32,32,128)
    const float* cent = (const float*)d_in[1];   // (32,64,128)
    float* out = (float*)d_out;                  // (32,8192)

    char* ws = (char*)d_ws;
    const size_t partial_bytes = (size_t)NB * SPLIT * 64 * 128 * sizeof(float);  // 16 MB
    const size_t cws_bytes     = (size_t)NB * 4096 * sizeof(ushort4);            // 1 MB
    const size_t c2_bytes      = (size_t)NB * 64 * sizeof(float);                // 8 KB
    const size_t vlad_bytes    = (size_t)NB * 64 * 128 * sizeof(float);          // 1 MB
    const size_t ssum_bytes    = (size_t)NB * SPLIT * 64 * sizeof(float);        // 128 KB

    float*   partial = (float*)ws;
    ushort4* cwsp    = (ushort4*)(ws + partial_bytes);
    float*   c2G     = (float*)(ws + partial_bytes + cws_bytes);
    float*   vlad    = (float*)(ws + partial_bytes + cws_bytes + c2_bytes);
    float*   ssumG   = (float*)(ws + partial_bytes + cws_bytes + c2_bytes + vlad_bytes);
    float*   sqpart  = (float*)(ws + partial_bytes + cws_bytes + c2_bytes + vlad_bytes + ssum_bytes);

    netvlad_prep  <<<256, 256, 0, stream>>>(cent, cwsp, c2G);
    netvlad_main  <<<NB * SPLIT, 256, 0, stream>>>(feat, cwsp, c2G, partial, ssumG);
    netvlad_reduce<<<256, 256, 0, stream>>>(partial, cent, ssumG, vlad, sqpart);
    netvlad_norm  <<<256, 256, 0, stream>>>(vlad, sqpart, out);
}